// Round 8
// baseline (552.435 us; speedup 1.0000x reference)
//
#include <hip/hip_runtime.h>
#include <hip/hip_bf16.h>

#define NN 50000
#define NE 800000
#define HD 128
#define BN_EPS 1e-5f
#define NB_SCAN 196  // ceil(NN/256)

typedef __attribute__((ext_vector_type(8))) __bf16 bf16x8;
typedef __attribute__((ext_vector_type(4))) float floatx4;

// ---------------- zero helpers ----------------
__global__ void k_zero_f(float* __restrict__ p, int n) {
    const int i = blockIdx.x * 256 + threadIdx.x;
    if (i < n) p[i] = 0.f;
}
__global__ void k_zero_i(int* __restrict__ p, int n) {
    const int i = blockIdx.x * 256 + threadIdx.x;
    if (i < n) p[i] = 0;
}

// ---------------- W prep: split into bf16 hi/lo, transposed [n][k] ----------------
// blockIdx.x = n, blockIdx.y = matrix index; thread t = k.
__global__ void k_wprep(const float* __restrict__ W0, const float* __restrict__ W1,
                        const float* __restrict__ W2, const float* __restrict__ W3,
                        const float* __restrict__ W4,
                        __bf16* __restrict__ Wth, __bf16* __restrict__ Wtl) {
    const int n = blockIdx.x, m = blockIdx.y, k = threadIdx.x;
    const float* W = (m == 0) ? W0 : (m == 1) ? W1 : (m == 2) ? W2 : (m == 3) ? W3 : W4;
    const float w = W[k * HD + n];
    const __bf16 h = (__bf16)w;
    const size_t o = (size_t)m * HD * HD + n * HD + k;
    Wth[o] = h;
    Wtl[o] = (__bf16)(w - (float)h);
}

// ---------------- CSR build: histogram of dst ----------------
__global__ void k_hist(const int* __restrict__ dst, int* __restrict__ deg) {
    const int e = blockIdx.x * 256 + threadIdx.x;
    atomicAdd(&deg[dst[e]], 1);
}

// ---------------- scan phase A: per-block sums of deg ----------------
__global__ __launch_bounds__(256) void k_blocksum(const int* __restrict__ deg,
                                                  int* __restrict__ bsum) {
    __shared__ int sh[256];
    const int t = threadIdx.x;
    const int i = blockIdx.x * 256 + t;
    sh[t] = (i < NN) ? deg[i] : 0;
    __syncthreads();
#pragma unroll
    for (int s = 128; s > 0; s >>= 1) {
        if (t < s) sh[t] += sh[t + s];
        __syncthreads();
    }
    if (t == 0) bsum[blockIdx.x] = sh[0];
}

// ---------------- scan phase B: exclusive scan of block sums (1 block) ----------------
__global__ __launch_bounds__(256) void k_scanpart(const int* __restrict__ bsum,
                                                  int* __restrict__ bbase) {
    __shared__ int sh[256];
    const int t = threadIdx.x;
    const int v = (t < NB_SCAN) ? bsum[t] : 0;
    sh[t] = v;
    __syncthreads();
#pragma unroll
    for (int s = 1; s < 256; s <<= 1) {
        int add = (t >= s) ? sh[t - s] : 0;
        __syncthreads();
        sh[t] += add;
        __syncthreads();
    }
    if (t < NB_SCAN) bbase[t] = sh[t] - v;  // exclusive
}

// ---------------- scan phase C: local scan + offset -> rowptr, cur ----------------
__global__ __launch_bounds__(256) void k_scanfin(const int* __restrict__ deg,
                                                 const int* __restrict__ bbase,
                                                 int* __restrict__ rowptr,
                                                 int* __restrict__ cur) {
    __shared__ int sh[256];
    const int t = threadIdx.x;
    const int i = blockIdx.x * 256 + t;
    const int v = (i < NN) ? deg[i] : 0;
    sh[t] = v;
    __syncthreads();
#pragma unroll
    for (int s = 1; s < 256; s <<= 1) {
        int add = (t >= s) ? sh[t - s] : 0;
        __syncthreads();
        sh[t] += add;
        __syncthreads();
    }
    const int incl = sh[t] + bbase[blockIdx.x];
    if (i < NN) {
        const int excl = incl - v;
        rowptr[i] = excl;
        cur[i] = excl;
        if (i == NN - 1) rowptr[NN] = incl;
    }
}

// ---------------- CSR build: fill edge sources ----------------
__global__ void k_fill(const int* __restrict__ src, const int* __restrict__ dst,
                       int* __restrict__ cur, int* __restrict__ esrc) {
    const int e = blockIdx.x * 256 + threadIdx.x;
    const int p = atomicAdd(&cur[dst[e]], 1);
    esrc[p] = src[e];
}

// ---------------- gather-aggregate: H[i] = Z[i] + sum_{j->i} Z[j] ----------------
__global__ __launch_bounds__(256) void k_agg(const float* __restrict__ Z,
                                             const int* __restrict__ rowptr,
                                             const int* __restrict__ esrc,
                                             float* __restrict__ H) {
    const int g = threadIdx.x >> 5;          // group 0..7
    const int lc = threadIdx.x & 31;
    const int node = blockIdx.x * 8 + g;
    const int c4 = lc * 4;
    const int start = rowptr[node], end = rowptr[node + 1];
    float4 acc = *(const float4*)&Z[(size_t)node * HD + c4];
    int k = start;
    for (; k + 4 <= end; k += 4) {
        const int s0 = esrc[k], s1 = esrc[k + 1], s2 = esrc[k + 2], s3 = esrc[k + 3];
        const float4 v0 = *(const float4*)&Z[(size_t)s0 * HD + c4];
        const float4 v1 = *(const float4*)&Z[(size_t)s1 * HD + c4];
        const float4 v2 = *(const float4*)&Z[(size_t)s2 * HD + c4];
        const float4 v3 = *(const float4*)&Z[(size_t)s3 * HD + c4];
        acc.x += v0.x + v1.x + v2.x + v3.x;
        acc.y += v0.y + v1.y + v2.y + v3.y;
        acc.z += v0.z + v1.z + v2.z + v3.z;
        acc.w += v0.w + v1.w + v2.w + v3.w;
    }
    for (; k < end; ++k) {
        const int s = esrc[k];
        const float4 v = *(const float4*)&Z[(size_t)s * HD + c4];
        acc.x += v.x; acc.y += v.y; acc.z += v.z; acc.w += v.w;
    }
    *(float4*)&H[(size_t)node * HD + c4] = acc;
}

// ---------------- MFMA GEMM (bf16x3 split, LDS-free): C = act(A @ W + b) ----------------
// B (pre-split W^T hi/lo) read directly from global: 64 KB/plane, L2-resident across
// all 391 blocks. No LDS, no __syncthreads -> VGPR-bound occupancy, latency hidden.
// Fragment layouts (learn_hip m89/m91/m120): A[m=lane&15][k=(lane>>4)*8+j]; B[n=lane&15][k same];
// C/D: col=lane&15, row=(lane>>4)*4+reg.
template <int ACT>
__global__ __launch_bounds__(256, 4) void k_gemm_mfma(const float* __restrict__ A,
                                                      const __bf16* __restrict__ Wth,
                                                      const __bf16* __restrict__ Wtl,
                                                      const float* __restrict__ bias,
                                                      float* __restrict__ C) {
    const int tid = threadIdx.x;
    const int wid = tid >> 6, lane = tid & 63;
    const int lq = lane >> 4, lm = lane & 15;
    const int rowbase = blockIdx.x * 128 + wid * 32;
    const int r0 = min(rowbase + lm, NN - 1);       // clamped load rows (garbage rows never stored)
    const int r1 = min(rowbase + 16 + lm, NN - 1);

    floatx4 acc[2][8];
#pragma unroll
    for (int i = 0; i < 2; ++i)
#pragma unroll
        for (int j = 0; j < 8; ++j) acc[i][j] = (floatx4){0.f, 0.f, 0.f, 0.f};

#pragma unroll
    for (int ks = 0; ks < 4; ++ks) {
        const int kk = ks * 32 + lq * 8;
        const float4 a0a = *(const float4*)&A[(size_t)r0 * HD + kk];
        const float4 a0b = *(const float4*)&A[(size_t)r0 * HD + kk + 4];
        const float4 a1a = *(const float4*)&A[(size_t)r1 * HD + kk];
        const float4 a1b = *(const float4*)&A[(size_t)r1 * HD + kk + 4];
        bf16x8 ah0, al0, ah1, al1;
        {
            const float f0[8] = {a0a.x, a0a.y, a0a.z, a0a.w, a0b.x, a0b.y, a0b.z, a0b.w};
            const float f1[8] = {a1a.x, a1a.y, a1a.z, a1a.w, a1b.x, a1b.y, a1b.z, a1b.w};
#pragma unroll
            for (int j = 0; j < 8; ++j) {
                const __bf16 h0 = (__bf16)f0[j];
                ah0[j] = h0;
                al0[j] = (__bf16)(f0[j] - (float)h0);
                const __bf16 h1 = (__bf16)f1[j];
                ah1[j] = h1;
                al1[j] = (__bf16)(f1[j] - (float)h1);
            }
        }
#pragma unroll
        for (int ct = 0; ct < 8; ++ct) {
            const size_t bo = (size_t)(ct * 16 + lm) * HD + kk;
            const bf16x8 bh = *(const bf16x8*)&Wth[bo];
            const bf16x8 bl = *(const bf16x8*)&Wtl[bo];
            acc[0][ct] = __builtin_amdgcn_mfma_f32_16x16x32_bf16(al0, bh, acc[0][ct], 0, 0, 0);
            acc[0][ct] = __builtin_amdgcn_mfma_f32_16x16x32_bf16(ah0, bl, acc[0][ct], 0, 0, 0);
            acc[0][ct] = __builtin_amdgcn_mfma_f32_16x16x32_bf16(ah0, bh, acc[0][ct], 0, 0, 0);
            acc[1][ct] = __builtin_amdgcn_mfma_f32_16x16x32_bf16(al1, bh, acc[1][ct], 0, 0, 0);
            acc[1][ct] = __builtin_amdgcn_mfma_f32_16x16x32_bf16(ah1, bl, acc[1][ct], 0, 0, 0);
            acc[1][ct] = __builtin_amdgcn_mfma_f32_16x16x32_bf16(ah1, bh, acc[1][ct], 0, 0, 0);
        }
    }

#pragma unroll
    for (int rt = 0; rt < 2; ++rt) {
#pragma unroll
        for (int ct = 0; ct < 8; ++ct) {
            const int col = ct * 16 + lm;
            const float bcol = bias[col];
            const int rw = rowbase + rt * 16 + lq * 4;
            const floatx4 v = acc[rt][ct];
#pragma unroll
            for (int r = 0; r < 4; ++r) {
                float y = v[r] + bcol;
                if (ACT) y = fmaxf(y, 0.f);
                if (rw + r < NN) C[(size_t)(rw + r) * HD + col] = y;
            }
        }
    }
}

// ---------------- per-column sum / sumsq ----------------
__global__ void k_colstats(const float* __restrict__ X, float* __restrict__ sum,
                           float* __restrict__ sumsq) {
    __shared__ float sh[128], shq[128];
    const int col = threadIdx.x & 127, half = threadIdx.x >> 7;
    const int r0 = blockIdx.x * 256;
    const int r1 = min(r0 + 256, NN);
    float s = 0.f, q = 0.f;
    for (int r = r0 + half; r < r1; r += 2) {
        const float v = X[(size_t)r * HD + col];
        s += v;
        q = fmaf(v, v, q);
    }
    if (half) { sh[col] = s; shq[col] = q; }
    __syncthreads();
    if (!half) {
        atomicAdd(&sum[col], s + sh[col]);
        atomicAdd(&sumsq[col], q + shq[col]);
    }
}

// ---------------- BN finalize ----------------
__global__ void k_bnfin(const float* __restrict__ sum, const float* __restrict__ sumsq,
                        const float* __restrict__ gamma, const float* __restrict__ beta,
                        float* __restrict__ scale, float* __restrict__ shift) {
    const int c = threadIdx.x;
    const float mean = sum[c] * (1.f / NN);
    const float var = sumsq[c] * (1.f / NN) - mean * mean;
    const float sc = gamma[c] * rsqrtf(var + BN_EPS);
    scale[c] = sc;
    shift[c] = beta[c] - mean * sc;
}

// ---------------- BN apply (+ optional PReLU), float4, in-place capable ----------------
template <int PRELU>
__global__ void k_bnapply(const float* __restrict__ X, const float* __restrict__ scale,
                          const float* __restrict__ shift, float* __restrict__ Y,
                          const float* __restrict__ pa) {
    const int i4 = (blockIdx.x * 256 + threadIdx.x) * 4;
    const int c = i4 & 127;
    const float4 sc = *(const float4*)&scale[c];
    const float4 sh = *(const float4*)&shift[c];
    const float4 v = *(const float4*)&X[i4];
    float4 y;
    y.x = fmaf(v.x, sc.x, sh.x);
    y.y = fmaf(v.y, sc.y, sh.y);
    y.z = fmaf(v.z, sc.z, sh.z);
    y.w = fmaf(v.w, sc.w, sh.w);
    if (PRELU) {
        const float a = pa[0];
        if (y.x < 0.f) y.x *= a;
        if (y.y < 0.f) y.y *= a;
        if (y.z < 0.f) y.z *= a;
        if (y.w < 0.f) y.w *= a;
    }
    *(float4*)&Y[i4] = y;
}

extern "C" void kernel_launch(void* const* d_in, const int* in_sizes, int n_in,
                              void* d_out, int out_size, void* d_ws, size_t ws_size,
                              hipStream_t stream) {
    const float* x = (const float*)d_in[0];
    const int* ei = (const int*)d_in[1];
    const float* w0a = (const float*)d_in[2];
    const float* b0a = (const float*)d_in[3];
    const float* w0b = (const float*)d_in[4];
    const float* b0b = (const float*)d_in[5];
    const float* w1a = (const float*)d_in[6];
    const float* b1a = (const float*)d_in[7];
    const float* w1b = (const float*)d_in[8];
    const float* b1b = (const float*)d_in[9];
    const float* bng = (const float*)d_in[10];
    const float* bnb = (const float*)d_in[11];
    const float* pw  = (const float*)d_in[12];
    const float* pb  = (const float*)d_in[13];
    const float* pbng = (const float*)d_in[14];
    const float* pbnb = (const float*)d_in[15];
    const float* pa = (const float*)d_in[16];

    float* outZ = (float*)d_out;                    // (NN,128) f32 — z
    float* outP = outZ + (size_t)NN * HD;           // (NN,128) f32 — p (also MLP temp)

    float* ws = (float*)d_ws;
    float* bufH = ws;                               // (NN,128) f32 — aggregate
    float* st = bufH + (size_t)NN * HD;             // 1024 floats of stats
    int* deg = (int*)(st + 1024);                   // NN
    int* rowptr = deg + NN;                         // NN+1 (+pad)
    int* cur = rowptr + NN + 64;                    // NN
    int* esrc = cur + NN;                           // NE
    int* bsum = esrc + NE;                          // 256
    int* bbase = bsum + 256;                        // 256
    __bf16* wth = (__bf16*)(bbase + 256);           // 5*128*128 bf16 hi planes
    __bf16* wtl = wth + 5 * HD * HD;                // 5*128*128 bf16 lo planes

    const int* srcv = ei;
    const int* dstv = ei + NE;

    const int EB = NE / 256;                        // 3125 edge blocks
    const int NB = NB_SCAN;                         // 196 node blocks
    const int ELV = (NN * HD) / (256 * 4);          // 6250 float4 elementwise blocks
    const int GB = (NN + 127) / 128;                // 391 GEMM blocks
    const int AB = NN / 8;                          // 6250 agg blocks

    // ---- W pre-split + CSR build (dst-sorted) + stat zeroing ----
    k_wprep<<<dim3(HD, 5), HD, 0, stream>>>(w0a, w0b, w1a, w1b, pw, wth, wtl);
    k_zero_f<<<4, 256, 0, stream>>>(st, 1024);
    k_zero_i<<<NB, 256, 0, stream>>>(deg, NN);
    k_hist<<<EB, 256, 0, stream>>>(dstv, deg);
    k_blocksum<<<NB, 256, 0, stream>>>(deg, bsum);
    k_scanpart<<<1, 256, 0, stream>>>(bsum, bbase);
    k_scanfin<<<NB, 256, 0, stream>>>(deg, bbase, rowptr, cur);
    k_fill<<<EB, 256, 0, stream>>>(srcv, dstv, cur, esrc);

    // ---- GIN layer 0 ----
    k_agg<<<AB, 256, 0, stream>>>(x, rowptr, esrc, bufH);
    k_gemm_mfma<1><<<GB, 256, 0, stream>>>(bufH, wth + 0 * HD * HD, wtl + 0 * HD * HD, b0a, outP);
    k_gemm_mfma<1><<<GB, 256, 0, stream>>>(outP, wth + 1 * HD * HD, wtl + 1 * HD * HD, b0b, outZ);

    // ---- GIN layer 1 ----
    k_agg<<<AB, 256, 0, stream>>>(outZ, rowptr, esrc, bufH);
    k_gemm_mfma<1><<<GB, 256, 0, stream>>>(bufH, wth + 2 * HD * HD, wtl + 2 * HD * HD, b1a, outP);
    k_gemm_mfma<1><<<GB, 256, 0, stream>>>(outP, wth + 3 * HD * HD, wtl + 3 * HD * HD, b1b, outZ);

    // ---- encoder BatchNorm -> z output (in place) ----
    k_colstats<<<NB, 256, 0, stream>>>(outZ, st + 0, st + 128);
    k_bnfin<<<1, 128, 0, stream>>>(st + 0, st + 128, bng, bnb, st + 256, st + 384);
    k_bnapply<0><<<ELV, 256, 0, stream>>>(outZ, st + 256, st + 384, outZ, pa);

    // ---- projection head: linear -> BN -> PReLU -> p output (in place) ----
    k_gemm_mfma<0><<<GB, 256, 0, stream>>>(outZ, wth + 4 * HD * HD, wtl + 4 * HD * HD, pb, outP);
    k_colstats<<<NB, 256, 0, stream>>>(outP, st + 512, st + 640);
    k_bnfin<<<1, 128, 0, stream>>>(st + 512, st + 640, pbng, pbnb, st + 768, st + 896);
    k_bnapply<1><<<ELV, 256, 0, stream>>>(outP, st + 768, st + 896, outP, pa);
}

// Round 9
// 497.465 us; speedup vs baseline: 1.1105x; 1.1105x over previous
//
#include <hip/hip_runtime.h>
#include <hip/hip_bf16.h>

#define NN 50000
#define NE 800000
#define HD 128
#define BN_EPS 1e-5f
#define NB_SCAN 196  // ceil(NN/256)

typedef __attribute__((ext_vector_type(8))) __bf16 bf16x8;
typedef __attribute__((ext_vector_type(4))) float floatx4;

// ---------------- zero helpers ----------------
__global__ void k_zero_f(float* __restrict__ p, int n) {
    const int i = blockIdx.x * 256 + threadIdx.x;
    if (i < n) p[i] = 0.f;
}
__global__ void k_zero_i(int* __restrict__ p, int n) {
    const int i = blockIdx.x * 256 + threadIdx.x;
    if (i < n) p[i] = 0;
}

// ---------------- W prep: split bf16 hi/lo, packed in wave-load order ----------------
// For MFMA B-fragment (n = lane&15, k = (lane>>4)*8 + j within a 32-k slice):
// offset(m, n, k) = m*HD*HD + ((ct*4 + ks)*64 + lane)*8 + j
//   ct = n>>4, lm = n&15, ks = k>>5, lq = (k&31)>>3, j = k&7, lane = lq*16+lm.
// Every B-load in the GEMM is then one contiguous 1 KB line per wave.
__global__ void k_wprep(const float* __restrict__ W0, const float* __restrict__ W1,
                        const float* __restrict__ W2, const float* __restrict__ W3,
                        const float* __restrict__ W4,
                        __bf16* __restrict__ Bh, __bf16* __restrict__ Bl) {
    const int n = blockIdx.x, m = blockIdx.y, k = threadIdx.x;
    const float* W = (m == 0) ? W0 : (m == 1) ? W1 : (m == 2) ? W2 : (m == 3) ? W3 : W4;
    const float w = W[k * HD + n];
    const __bf16 h = (__bf16)w;
    const int ct = n >> 4, lm = n & 15;
    const int ks = k >> 5, lq = (k & 31) >> 3, j = k & 7;
    const int lane = lq * 16 + lm;
    const size_t o = (size_t)m * HD * HD + (size_t)(((ct * 4 + ks) * 64) + lane) * 8 + j;
    Bh[o] = h;
    Bl[o] = (__bf16)(w - (float)h);
}

// ---------------- CSR build: histogram of dst ----------------
__global__ void k_hist(const int* __restrict__ dst, int* __restrict__ deg) {
    const int e = blockIdx.x * 256 + threadIdx.x;
    atomicAdd(&deg[dst[e]], 1);
}

// ---------------- scan phase A: per-block sums of deg ----------------
__global__ __launch_bounds__(256) void k_blocksum(const int* __restrict__ deg,
                                                  int* __restrict__ bsum) {
    __shared__ int sh[256];
    const int t = threadIdx.x;
    const int i = blockIdx.x * 256 + t;
    sh[t] = (i < NN) ? deg[i] : 0;
    __syncthreads();
#pragma unroll
    for (int s = 128; s > 0; s >>= 1) {
        if (t < s) sh[t] += sh[t + s];
        __syncthreads();
    }
    if (t == 0) bsum[blockIdx.x] = sh[0];
}

// ---------------- scan phase B: exclusive scan of block sums (1 block) ----------------
__global__ __launch_bounds__(256) void k_scanpart(const int* __restrict__ bsum,
                                                  int* __restrict__ bbase) {
    __shared__ int sh[256];
    const int t = threadIdx.x;
    const int v = (t < NB_SCAN) ? bsum[t] : 0;
    sh[t] = v;
    __syncthreads();
#pragma unroll
    for (int s = 1; s < 256; s <<= 1) {
        int add = (t >= s) ? sh[t - s] : 0;
        __syncthreads();
        sh[t] += add;
        __syncthreads();
    }
    if (t < NB_SCAN) bbase[t] = sh[t] - v;  // exclusive
}

// ---------------- scan phase C: local scan + offset -> rowptr, cur ----------------
__global__ __launch_bounds__(256) void k_scanfin(const int* __restrict__ deg,
                                                 const int* __restrict__ bbase,
                                                 int* __restrict__ rowptr,
                                                 int* __restrict__ cur) {
    __shared__ int sh[256];
    const int t = threadIdx.x;
    const int i = blockIdx.x * 256 + t;
    const int v = (i < NN) ? deg[i] : 0;
    sh[t] = v;
    __syncthreads();
#pragma unroll
    for (int s = 1; s < 256; s <<= 1) {
        int add = (t >= s) ? sh[t - s] : 0;
        __syncthreads();
        sh[t] += add;
        __syncthreads();
    }
    const int incl = sh[t] + bbase[blockIdx.x];
    if (i < NN) {
        const int excl = incl - v;
        rowptr[i] = excl;
        cur[i] = excl;
        if (i == NN - 1) rowptr[NN] = incl;
    }
}

// ---------------- CSR build: fill edge sources ----------------
__global__ void k_fill(const int* __restrict__ src, const int* __restrict__ dst,
                       int* __restrict__ cur, int* __restrict__ esrc) {
    const int e = blockIdx.x * 256 + threadIdx.x;
    const int p = atomicAdd(&cur[dst[e]], 1);
    esrc[p] = src[e];
}

// ---------------- gather-aggregate: H[i] = Z[i] + sum_{j->i} Z[j] ----------------
__global__ __launch_bounds__(256) void k_agg(const float* __restrict__ Z,
                                             const int* __restrict__ rowptr,
                                             const int* __restrict__ esrc,
                                             float* __restrict__ H) {
    const int g = threadIdx.x >> 5;          // group 0..7
    const int lc = threadIdx.x & 31;
    const int node = blockIdx.x * 8 + g;
    const int c4 = lc * 4;
    const int start = rowptr[node], end = rowptr[node + 1];
    float4 acc = *(const float4*)&Z[(size_t)node * HD + c4];
    int k = start;
    for (; k + 4 <= end; k += 4) {
        const int s0 = esrc[k], s1 = esrc[k + 1], s2 = esrc[k + 2], s3 = esrc[k + 3];
        const float4 v0 = *(const float4*)&Z[(size_t)s0 * HD + c4];
        const float4 v1 = *(const float4*)&Z[(size_t)s1 * HD + c4];
        const float4 v2 = *(const float4*)&Z[(size_t)s2 * HD + c4];
        const float4 v3 = *(const float4*)&Z[(size_t)s3 * HD + c4];
        acc.x += v0.x + v1.x + v2.x + v3.x;
        acc.y += v0.y + v1.y + v2.y + v3.y;
        acc.z += v0.z + v1.z + v2.z + v3.z;
        acc.w += v0.w + v1.w + v2.w + v3.w;
    }
    for (; k < end; ++k) {
        const int s = esrc[k];
        const float4 v = *(const float4*)&Z[(size_t)s * HD + c4];
        acc.x += v.x; acc.y += v.y; acc.z += v.z; acc.w += v.w;
    }
    *(float4*)&H[(size_t)node * HD + c4] = acc;
}

// ---------------- slim-wave MFMA GEMM (bf16x3 split): C = act(A @ W + b) ----------------
// 16 rows per wave, 64 per block, 782 blocks (3 blocks/CU, 12 waves/CU).
// acc[8] only (~32 VGPRs) + explicit element-wise split (no local arrays, no spill risk).
// B pre-packed in wave-load order by k_wprep: every B-load = contiguous 1 KB per wave, L2-hot.
// Fragments (learn_hip m89/m91): A[m=lane&15][k=(lane>>4)*8+j]; B[n=lane&15][k same];
// C/D: col=lane&15, row=(lane>>4)*4+reg.
template <int ACT>
__global__ __launch_bounds__(256) void k_gemm_mfma(const float* __restrict__ A,
                                                   const __bf16* __restrict__ Bh,
                                                   const __bf16* __restrict__ Bl,
                                                   const float* __restrict__ bias,
                                                   float* __restrict__ C) {
    const int tid = threadIdx.x;
    const int wid = tid >> 6, lane = tid & 63;
    const int lq = lane >> 4, lm = lane & 15;
    const int rowbase = blockIdx.x * 64 + wid * 16;
    const int r0 = min(rowbase + lm, NN - 1);   // clamped; garbage rows never stored

    floatx4 acc[8];
#pragma unroll
    for (int j = 0; j < 8; ++j) acc[j] = (floatx4){0.f, 0.f, 0.f, 0.f};

#pragma unroll
    for (int ks = 0; ks < 4; ++ks) {
        const int kk = ks * 32 + lq * 8;
        const float4 aa = *(const float4*)&A[(size_t)r0 * HD + kk];
        const float4 ab = *(const float4*)&A[(size_t)r0 * HD + kk + 4];
        bf16x8 ah, al;
        ah[0] = (__bf16)aa.x; al[0] = (__bf16)(aa.x - (float)ah[0]);
        ah[1] = (__bf16)aa.y; al[1] = (__bf16)(aa.y - (float)ah[1]);
        ah[2] = (__bf16)aa.z; al[2] = (__bf16)(aa.z - (float)ah[2]);
        ah[3] = (__bf16)aa.w; al[3] = (__bf16)(aa.w - (float)ah[3]);
        ah[4] = (__bf16)ab.x; al[4] = (__bf16)(ab.x - (float)ah[4]);
        ah[5] = (__bf16)ab.y; al[5] = (__bf16)(ab.y - (float)ah[5]);
        ah[6] = (__bf16)ab.z; al[6] = (__bf16)(ab.z - (float)ah[6]);
        ah[7] = (__bf16)ab.w; al[7] = (__bf16)(ab.w - (float)ah[7]);
#pragma unroll
        for (int ct = 0; ct < 8; ++ct) {
            const size_t bo = (size_t)(((ct * 4 + ks) * 64) + lane) * 8;
            const bf16x8 bh = *(const bf16x8*)&Bh[bo];
            const bf16x8 bl = *(const bf16x8*)&Bl[bo];
            acc[ct] = __builtin_amdgcn_mfma_f32_16x16x32_bf16(al, bh, acc[ct], 0, 0, 0);
            acc[ct] = __builtin_amdgcn_mfma_f32_16x16x32_bf16(ah, bl, acc[ct], 0, 0, 0);
            acc[ct] = __builtin_amdgcn_mfma_f32_16x16x32_bf16(ah, bh, acc[ct], 0, 0, 0);
        }
    }

    const int rw = rowbase + lq * 4;
#pragma unroll
    for (int ct = 0; ct < 8; ++ct) {
        const int col = ct * 16 + lm;
        const float bcol = bias[col];
        const floatx4 v = acc[ct];
#pragma unroll
        for (int r = 0; r < 4; ++r) {
            float y = v[r] + bcol;
            if (ACT) y = fmaxf(y, 0.f);
            if (rw + r < NN) C[(size_t)(rw + r) * HD + col] = y;
        }
    }
}

// ---------------- per-column sum / sumsq ----------------
__global__ void k_colstats(const float* __restrict__ X, float* __restrict__ sum,
                           float* __restrict__ sumsq) {
    __shared__ float sh[128], shq[128];
    const int col = threadIdx.x & 127, half = threadIdx.x >> 7;
    const int r0 = blockIdx.x * 256;
    const int r1 = min(r0 + 256, NN);
    float s = 0.f, q = 0.f;
    for (int r = r0 + half; r < r1; r += 2) {
        const float v = X[(size_t)r * HD + col];
        s += v;
        q = fmaf(v, v, q);
    }
    if (half) { sh[col] = s; shq[col] = q; }
    __syncthreads();
    if (!half) {
        atomicAdd(&sum[col], s + sh[col]);
        atomicAdd(&sumsq[col], q + shq[col]);
    }
}

// ---------------- BN finalize ----------------
__global__ void k_bnfin(const float* __restrict__ sum, const float* __restrict__ sumsq,
                        const float* __restrict__ gamma, const float* __restrict__ beta,
                        float* __restrict__ scale, float* __restrict__ shift) {
    const int c = threadIdx.x;
    const float mean = sum[c] * (1.f / NN);
    const float var = sumsq[c] * (1.f / NN) - mean * mean;
    const float sc = gamma[c] * rsqrtf(var + BN_EPS);
    scale[c] = sc;
    shift[c] = beta[c] - mean * sc;
}

// ---------------- BN apply (+ optional PReLU), float4, in-place capable ----------------
template <int PRELU>
__global__ void k_bnapply(const float* __restrict__ X, const float* __restrict__ scale,
                          const float* __restrict__ shift, float* __restrict__ Y,
                          const float* __restrict__ pa) {
    const int i4 = (blockIdx.x * 256 + threadIdx.x) * 4;
    const int c = i4 & 127;
    const float4 sc = *(const float4*)&scale[c];
    const float4 sh = *(const float4*)&shift[c];
    const float4 v = *(const float4*)&X[i4];
    float4 y;
    y.x = fmaf(v.x, sc.x, sh.x);
    y.y = fmaf(v.y, sc.y, sh.y);
    y.z = fmaf(v.z, sc.z, sh.z);
    y.w = fmaf(v.w, sc.w, sh.w);
    if (PRELU) {
        const float a = pa[0];
        if (y.x < 0.f) y.x *= a;
        if (y.y < 0.f) y.y *= a;
        if (y.z < 0.f) y.z *= a;
        if (y.w < 0.f) y.w *= a;
    }
    *(float4*)&Y[i4] = y;
}

extern "C" void kernel_launch(void* const* d_in, const int* in_sizes, int n_in,
                              void* d_out, int out_size, void* d_ws, size_t ws_size,
                              hipStream_t stream) {
    const float* x = (const float*)d_in[0];
    const int* ei = (const int*)d_in[1];
    const float* w0a = (const float*)d_in[2];
    const float* b0a = (const float*)d_in[3];
    const float* w0b = (const float*)d_in[4];
    const float* b0b = (const float*)d_in[5];
    const float* w1a = (const float*)d_in[6];
    const float* b1a = (const float*)d_in[7];
    const float* w1b = (const float*)d_in[8];
    const float* b1b = (const float*)d_in[9];
    const float* bng = (const float*)d_in[10];
    const float* bnb = (const float*)d_in[11];
    const float* pw  = (const float*)d_in[12];
    const float* pb  = (const float*)d_in[13];
    const float* pbng = (const float*)d_in[14];
    const float* pbnb = (const float*)d_in[15];
    const float* pa = (const float*)d_in[16];

    float* outZ = (float*)d_out;                    // (NN,128) f32 — z
    float* outP = outZ + (size_t)NN * HD;           // (NN,128) f32 — p (also MLP temp)

    float* ws = (float*)d_ws;
    float* bufH = ws;                               // (NN,128) f32 — aggregate
    float* st = bufH + (size_t)NN * HD;             // 1024 floats of stats
    int* deg = (int*)(st + 1024);                   // NN
    int* rowptr = deg + NN;                         // NN+1 (+pad)
    int* cur = rowptr + NN + 64;                    // NN
    int* esrc = cur + NN;                           // NE
    int* bsum = esrc + NE;                          // 256
    int* bbase = bsum + 256;                        // 256
    __bf16* wth = (__bf16*)(bbase + 256);           // 5*128*128 bf16 hi (packed)
    __bf16* wtl = wth + 5 * HD * HD;                // 5*128*128 bf16 lo (packed)

    const int* srcv = ei;
    const int* dstv = ei + NE;

    const int EB = NE / 256;                        // 3125 edge blocks
    const int NB = NB_SCAN;                         // 196 node blocks
    const int ELV = (NN * HD) / (256 * 4);          // 6250 float4 elementwise blocks
    const int GB = (NN + 63) / 64;                  // 782 GEMM blocks
    const int AB = NN / 8;                          // 6250 agg blocks

    // ---- W pre-split/pack + CSR build (dst-sorted) + stat zeroing ----
    k_wprep<<<dim3(HD, 5), HD, 0, stream>>>(w0a, w0b, w1a, w1b, pw, wth, wtl);
    k_zero_f<<<4, 256, 0, stream>>>(st, 1024);
    k_zero_i<<<NB, 256, 0, stream>>>(deg, NN);
    k_hist<<<EB, 256, 0, stream>>>(dstv, deg);
    k_blocksum<<<NB, 256, 0, stream>>>(deg, bsum);
    k_scanpart<<<1, 256, 0, stream>>>(bsum, bbase);
    k_scanfin<<<NB, 256, 0, stream>>>(deg, bbase, rowptr, cur);
    k_fill<<<EB, 256, 0, stream>>>(srcv, dstv, cur, esrc);

    // ---- GIN layer 0 ----
    k_agg<<<AB, 256, 0, stream>>>(x, rowptr, esrc, bufH);
    k_gemm_mfma<1><<<GB, 256, 0, stream>>>(bufH, wth + 0 * HD * HD, wtl + 0 * HD * HD, b0a, outP);
    k_gemm_mfma<1><<<GB, 256, 0, stream>>>(outP, wth + 1 * HD * HD, wtl + 1 * HD * HD, b0b, outZ);

    // ---- GIN layer 1 ----
    k_agg<<<AB, 256, 0, stream>>>(outZ, rowptr, esrc, bufH);
    k_gemm_mfma<1><<<GB, 256, 0, stream>>>(bufH, wth + 2 * HD * HD, wtl + 2 * HD * HD, b1a, outP);
    k_gemm_mfma<1><<<GB, 256, 0, stream>>>(outP, wth + 3 * HD * HD, wtl + 3 * HD * HD, b1b, outZ);

    // ---- encoder BatchNorm -> z output (in place) ----
    k_colstats<<<NB, 256, 0, stream>>>(outZ, st + 0, st + 128);
    k_bnfin<<<1, 128, 0, stream>>>(st + 0, st + 128, bng, bnb, st + 256, st + 384);
    k_bnapply<0><<<ELV, 256, 0, stream>>>(outZ, st + 256, st + 384, outZ, pa);

    // ---- projection head: linear -> BN -> PReLU -> p output (in place) ----
    k_gemm_mfma<0><<<GB, 256, 0, stream>>>(outZ, wth + 4 * HD * HD, wtl + 4 * HD * HD, pb, outP);
    k_colstats<<<NB, 256, 0, stream>>>(outP, st + 512, st + 640);
    k_bnfin<<<1, 128, 0, stream>>>(st + 512, st + 640, pbng, pbnb, st + 768, st + 896);
    k_bnapply<1><<<ELV, 256, 0, stream>>>(outP, st + 768, st + 896, outP, pa);
}

// Round 10
// 472.637 us; speedup vs baseline: 1.1688x; 1.0525x over previous
//
#include <hip/hip_runtime.h>
#include <hip/hip_bf16.h>

#define NN 50000
#define NE 800000
#define HD 128
#define BN_EPS 1e-5f
#define NB_SCAN 196  // ceil(NN/256)
#define MSTR 132     // padded LDS mid stride (floats)

typedef __attribute__((ext_vector_type(8))) __bf16 bf16x8;
typedef __attribute__((ext_vector_type(4))) float floatx4;

// ---------------- zero helpers ----------------
__global__ void k_zero_f(float* __restrict__ p, int n) {
    const int i = blockIdx.x * 256 + threadIdx.x;
    if (i < n) p[i] = 0.f;
}
__global__ void k_zero_i(int* __restrict__ p, int n) {
    const int i = blockIdx.x * 256 + threadIdx.x;
    if (i < n) p[i] = 0;
}

// ---------------- W prep: split bf16 hi/lo, packed in wave-load order ----------------
// offset(m, n, k) = m*HD*HD + ((ct*4 + ks)*64 + lane)*8 + j  (see R8 notes)
__global__ void k_wprep(const float* __restrict__ W0, const float* __restrict__ W1,
                        const float* __restrict__ W2, const float* __restrict__ W3,
                        const float* __restrict__ W4,
                        __bf16* __restrict__ Bh, __bf16* __restrict__ Bl) {
    const int n = blockIdx.x, m = blockIdx.y, k = threadIdx.x;
    const float* W = (m == 0) ? W0 : (m == 1) ? W1 : (m == 2) ? W2 : (m == 3) ? W3 : W4;
    const float w = W[k * HD + n];
    const __bf16 h = (__bf16)w;
    const int ct = n >> 4, lm = n & 15;
    const int ks = k >> 5, lq = (k & 31) >> 3, j = k & 7;
    const int lane = lq * 16 + lm;
    const size_t o = (size_t)m * HD * HD + (size_t)(((ct * 4 + ks) * 64) + lane) * 8 + j;
    Bh[o] = h;
    Bl[o] = (__bf16)(w - (float)h);
}

// ---------------- CSR build ----------------
__global__ void k_hist(const int* __restrict__ dst, int* __restrict__ deg) {
    const int e = blockIdx.x * 256 + threadIdx.x;
    atomicAdd(&deg[dst[e]], 1);
}

__global__ __launch_bounds__(256) void k_blocksum(const int* __restrict__ deg,
                                                  int* __restrict__ bsum) {
    __shared__ int sh[256];
    const int t = threadIdx.x;
    const int i = blockIdx.x * 256 + t;
    sh[t] = (i < NN) ? deg[i] : 0;
    __syncthreads();
#pragma unroll
    for (int s = 128; s > 0; s >>= 1) {
        if (t < s) sh[t] += sh[t + s];
        __syncthreads();
    }
    if (t == 0) bsum[blockIdx.x] = sh[0];
}

__global__ __launch_bounds__(256) void k_scanpart(const int* __restrict__ bsum,
                                                  int* __restrict__ bbase) {
    __shared__ int sh[256];
    const int t = threadIdx.x;
    const int v = (t < NB_SCAN) ? bsum[t] : 0;
    sh[t] = v;
    __syncthreads();
#pragma unroll
    for (int s = 1; s < 256; s <<= 1) {
        int add = (t >= s) ? sh[t - s] : 0;
        __syncthreads();
        sh[t] += add;
        __syncthreads();
    }
    if (t < NB_SCAN) bbase[t] = sh[t] - v;  // exclusive
}

__global__ __launch_bounds__(256) void k_scanfin(const int* __restrict__ deg,
                                                 const int* __restrict__ bbase,
                                                 int* __restrict__ rowptr,
                                                 int* __restrict__ cur) {
    __shared__ int sh[256];
    const int t = threadIdx.x;
    const int i = blockIdx.x * 256 + t;
    const int v = (i < NN) ? deg[i] : 0;
    sh[t] = v;
    __syncthreads();
#pragma unroll
    for (int s = 1; s < 256; s <<= 1) {
        int add = (t >= s) ? sh[t - s] : 0;
        __syncthreads();
        sh[t] += add;
        __syncthreads();
    }
    const int incl = sh[t] + bbase[blockIdx.x];
    if (i < NN) {
        const int excl = incl - v;
        rowptr[i] = excl;
        cur[i] = excl;
        if (i == NN - 1) rowptr[NN] = incl;
    }
}

__global__ void k_fill(const int* __restrict__ src, const int* __restrict__ dst,
                       int* __restrict__ cur, int* __restrict__ esrc) {
    const int e = blockIdx.x * 256 + threadIdx.x;
    const int p = atomicAdd(&cur[dst[e]], 1);
    esrc[p] = src[e];
}

// ---------------- gather-aggregate: H[i] = Z[i] + sum_{j->i} Z[j] ----------------
__global__ __launch_bounds__(256) void k_agg(const float* __restrict__ Z,
                                             const int* __restrict__ rowptr,
                                             const int* __restrict__ esrc,
                                             float* __restrict__ H) {
    const int g = threadIdx.x >> 5;
    const int lc = threadIdx.x & 31;
    const int node = blockIdx.x * 8 + g;
    const int c4 = lc * 4;
    const int start = rowptr[node], end = rowptr[node + 1];
    float4 acc = *(const float4*)&Z[(size_t)node * HD + c4];
    int k = start;
    for (; k + 4 <= end; k += 4) {
        const int s0 = esrc[k], s1 = esrc[k + 1], s2 = esrc[k + 2], s3 = esrc[k + 3];
        const float4 v0 = *(const float4*)&Z[(size_t)s0 * HD + c4];
        const float4 v1 = *(const float4*)&Z[(size_t)s1 * HD + c4];
        const float4 v2 = *(const float4*)&Z[(size_t)s2 * HD + c4];
        const float4 v3 = *(const float4*)&Z[(size_t)s3 * HD + c4];
        acc.x += v0.x + v1.x + v2.x + v3.x;
        acc.y += v0.y + v1.y + v2.y + v3.y;
        acc.z += v0.z + v1.z + v2.z + v3.z;
        acc.w += v0.w + v1.w + v2.w + v3.w;
    }
    for (; k < end; ++k) {
        const int s = esrc[k];
        const float4 v = *(const float4*)&Z[(size_t)s * HD + c4];
        acc.x += v.x; acc.y += v.y; acc.z += v.z; acc.w += v.w;
    }
    *(float4*)&H[(size_t)node * HD + c4] = acc;
}

// ---------------- helper: split float8 into bf16 hi/lo fragments ----------------
__device__ __forceinline__ void split8(const float4 a, const float4 b,
                                       bf16x8& hi, bf16x8& lo) {
    hi[0] = (__bf16)a.x; lo[0] = (__bf16)(a.x - (float)hi[0]);
    hi[1] = (__bf16)a.y; lo[1] = (__bf16)(a.y - (float)hi[1]);
    hi[2] = (__bf16)a.z; lo[2] = (__bf16)(a.z - (float)hi[2]);
    hi[3] = (__bf16)a.w; lo[3] = (__bf16)(a.w - (float)hi[3]);
    hi[4] = (__bf16)b.x; lo[4] = (__bf16)(b.x - (float)hi[4]);
    hi[5] = (__bf16)b.y; lo[5] = (__bf16)(b.y - (float)hi[5]);
    hi[6] = (__bf16)b.z; lo[6] = (__bf16)(b.z - (float)hi[6]);
    hi[7] = (__bf16)b.w; lo[7] = (__bf16)(b.w - (float)hi[7]);
}

// ---------------- fused GIN MLP: C = relu(relu(A@W1+b1)@W2+b2), optional col stats ----------------
// 4 waves x 16 rows; mid stays in per-wave LDS (16 x MSTR f32) -> GEMM2 has no global A-load.
// Fragments (learn_hip m89/m91): A[m=lane&15][k=(lane>>4)*8+j]; C/D col=lane&15, row=(lane>>4)*4+reg.
template <int STATS>
__global__ __launch_bounds__(256) void k_mlp(const float* __restrict__ A,
                                             const __bf16* __restrict__ Bh1,
                                             const __bf16* __restrict__ Bl1,
                                             const float* __restrict__ b1,
                                             const __bf16* __restrict__ Bh2,
                                             const __bf16* __restrict__ Bl2,
                                             const float* __restrict__ b2,
                                             float* __restrict__ C,
                                             float* __restrict__ gsum,
                                             float* __restrict__ gsq) {
    __shared__ float mid[4][16 * MSTR];   // 33792 B
    __shared__ float ssum[128], ssq[128]; // stats staging
    const int tid = threadIdx.x;
    const int wid = tid >> 6, lane = tid & 63;
    const int lq = lane >> 4, lm = lane & 15;
    if (STATS) {
        if (tid < 128) { ssum[tid] = 0.f; ssq[tid] = 0.f; }
        __syncthreads();
    }
    const int rowbase = blockIdx.x * 64 + wid * 16;
    const int r0 = min(rowbase + lm, NN - 1);

    // ---- GEMM1: mid = relu(A@W1 + b1) ----
    floatx4 acc[8];
#pragma unroll
    for (int j = 0; j < 8; ++j) acc[j] = (floatx4){0.f, 0.f, 0.f, 0.f};
#pragma unroll
    for (int ks = 0; ks < 4; ++ks) {
        const int kk = ks * 32 + lq * 8;
        const float4 aa = *(const float4*)&A[(size_t)r0 * HD + kk];
        const float4 ab = *(const float4*)&A[(size_t)r0 * HD + kk + 4];
        bf16x8 ah, al;
        split8(aa, ab, ah, al);
#pragma unroll
        for (int ct = 0; ct < 8; ++ct) {
            const size_t bo = (size_t)(((ct * 4 + ks) * 64) + lane) * 8;
            const bf16x8 bh = *(const bf16x8*)&Bh1[bo];
            const bf16x8 bl = *(const bf16x8*)&Bl1[bo];
            acc[ct] = __builtin_amdgcn_mfma_f32_16x16x32_bf16(al, bh, acc[ct], 0, 0, 0);
            acc[ct] = __builtin_amdgcn_mfma_f32_16x16x32_bf16(ah, bl, acc[ct], 0, 0, 0);
            acc[ct] = __builtin_amdgcn_mfma_f32_16x16x32_bf16(ah, bh, acc[ct], 0, 0, 0);
        }
    }
    // bias + relu -> per-wave LDS mid (row-major, stride MSTR)
    float* m = &mid[wid][0];
#pragma unroll
    for (int ct = 0; ct < 8; ++ct) {
        const int col = ct * 16 + lm;
        const float bcol = b1[col];
#pragma unroll
        for (int r = 0; r < 4; ++r) {
            m[(lq * 4 + r) * MSTR + col] = fmaxf(acc[ct][r] + bcol, 0.f);
        }
    }
    // ---- GEMM2: C = relu(mid@W2 + b2) ---- (A from LDS; per-wave region, no barrier)
#pragma unroll
    for (int j = 0; j < 8; ++j) acc[j] = (floatx4){0.f, 0.f, 0.f, 0.f};
#pragma unroll
    for (int ks = 0; ks < 4; ++ks) {
        const int kk = ks * 32 + lq * 8;
        const float4 aa = *(const float4*)&m[lm * MSTR + kk];
        const float4 ab = *(const float4*)&m[lm * MSTR + kk + 4];
        bf16x8 ah, al;
        split8(aa, ab, ah, al);
#pragma unroll
        for (int ct = 0; ct < 8; ++ct) {
            const size_t bo = (size_t)(((ct * 4 + ks) * 64) + lane) * 8;
            const bf16x8 bh = *(const bf16x8*)&Bh2[bo];
            const bf16x8 bl = *(const bf16x8*)&Bl2[bo];
            acc[ct] = __builtin_amdgcn_mfma_f32_16x16x32_bf16(al, bh, acc[ct], 0, 0, 0);
            acc[ct] = __builtin_amdgcn_mfma_f32_16x16x32_bf16(ah, bl, acc[ct], 0, 0, 0);
            acc[ct] = __builtin_amdgcn_mfma_f32_16x16x32_bf16(ah, bh, acc[ct], 0, 0, 0);
        }
    }
    const int rw = rowbase + lq * 4;
#pragma unroll
    for (int ct = 0; ct < 8; ++ct) {
        const int col = ct * 16 + lm;
        const float bcol = b2[col];
        float s = 0.f, q = 0.f;
#pragma unroll
        for (int r = 0; r < 4; ++r) {
            const float y = fmaxf(acc[ct][r] + bcol, 0.f);
            if (rw + r < NN) {
                C[(size_t)(rw + r) * HD + col] = y;
                if (STATS) { s += y; q = fmaf(y, y, q); }
            }
        }
        if (STATS) {
            s += __shfl_xor(s, 16); s += __shfl_xor(s, 32);
            q += __shfl_xor(q, 16); q += __shfl_xor(q, 32);
            if (lq == 0) { atomicAdd(&ssum[col], s); atomicAdd(&ssq[col], q); }
        }
    }
    if (STATS) {
        __syncthreads();
        if (tid < 128) {
            atomicAdd(&gsum[tid], ssum[tid]);
            atomicAdd(&gsq[tid], ssq[tid]);
        }
    }
}

// ---------------- projection GEMM: P = A@W + b (no act), fused col stats ----------------
__global__ __launch_bounds__(256) void k_proj(const float* __restrict__ A,
                                              const __bf16* __restrict__ Bh,
                                              const __bf16* __restrict__ Bl,
                                              const float* __restrict__ bias,
                                              float* __restrict__ C,
                                              float* __restrict__ gsum,
                                              float* __restrict__ gsq) {
    __shared__ float ssum[128], ssq[128];
    const int tid = threadIdx.x;
    const int wid = tid >> 6, lane = tid & 63;
    const int lq = lane >> 4, lm = lane & 15;
    if (tid < 128) { ssum[tid] = 0.f; ssq[tid] = 0.f; }
    __syncthreads();
    const int rowbase = blockIdx.x * 64 + wid * 16;
    const int r0 = min(rowbase + lm, NN - 1);

    floatx4 acc[8];
#pragma unroll
    for (int j = 0; j < 8; ++j) acc[j] = (floatx4){0.f, 0.f, 0.f, 0.f};
#pragma unroll
    for (int ks = 0; ks < 4; ++ks) {
        const int kk = ks * 32 + lq * 8;
        const float4 aa = *(const float4*)&A[(size_t)r0 * HD + kk];
        const float4 ab = *(const float4*)&A[(size_t)r0 * HD + kk + 4];
        bf16x8 ah, al;
        split8(aa, ab, ah, al);
#pragma unroll
        for (int ct = 0; ct < 8; ++ct) {
            const size_t bo = (size_t)(((ct * 4 + ks) * 64) + lane) * 8;
            const bf16x8 bh = *(const bf16x8*)&Bh[bo];
            const bf16x8 bl = *(const bf16x8*)&Bl[bo];
            acc[ct] = __builtin_amdgcn_mfma_f32_16x16x32_bf16(al, bh, acc[ct], 0, 0, 0);
            acc[ct] = __builtin_amdgcn_mfma_f32_16x16x32_bf16(ah, bl, acc[ct], 0, 0, 0);
            acc[ct] = __builtin_amdgcn_mfma_f32_16x16x32_bf16(ah, bh, acc[ct], 0, 0, 0);
        }
    }
    const int rw = rowbase + lq * 4;
#pragma unroll
    for (int ct = 0; ct < 8; ++ct) {
        const int col = ct * 16 + lm;
        const float bcol = bias[col];
        float s = 0.f, q = 0.f;
#pragma unroll
        for (int r = 0; r < 4; ++r) {
            const float y = acc[ct][r] + bcol;
            if (rw + r < NN) {
                C[(size_t)(rw + r) * HD + col] = y;
                s += y; q = fmaf(y, y, q);
            }
        }
        s += __shfl_xor(s, 16); s += __shfl_xor(s, 32);
        q += __shfl_xor(q, 16); q += __shfl_xor(q, 32);
        if (lq == 0) { atomicAdd(&ssum[col], s); atomicAdd(&ssq[col], q); }
    }
    __syncthreads();
    if (tid < 128) {
        atomicAdd(&gsum[tid], ssum[tid]);
        atomicAdd(&gsq[tid], ssq[tid]);
    }
}

// ---------------- BN finalize ----------------
__global__ void k_bnfin(const float* __restrict__ sum, const float* __restrict__ sumsq,
                        const float* __restrict__ gamma, const float* __restrict__ beta,
                        float* __restrict__ scale, float* __restrict__ shift) {
    const int c = threadIdx.x;
    const float mean = sum[c] * (1.f / NN);
    const float var = sumsq[c] * (1.f / NN) - mean * mean;
    const float sc = gamma[c] * rsqrtf(var + BN_EPS);
    scale[c] = sc;
    shift[c] = beta[c] - mean * sc;
}

// ---------------- BN apply (+ optional PReLU), float4, in-place capable ----------------
template <int PRELU>
__global__ void k_bnapply(const float* __restrict__ X, const float* __restrict__ scale,
                          const float* __restrict__ shift, float* __restrict__ Y,
                          const float* __restrict__ pa) {
    const int i4 = (blockIdx.x * 256 + threadIdx.x) * 4;
    const int c = i4 & 127;
    const float4 sc = *(const float4*)&scale[c];
    const float4 sh = *(const float4*)&shift[c];
    const float4 v = *(const float4*)&X[i4];
    float4 y;
    y.x = fmaf(v.x, sc.x, sh.x);
    y.y = fmaf(v.y, sc.y, sh.y);
    y.z = fmaf(v.z, sc.z, sh.z);
    y.w = fmaf(v.w, sc.w, sh.w);
    if (PRELU) {
        const float a = pa[0];
        if (y.x < 0.f) y.x *= a;
        if (y.y < 0.f) y.y *= a;
        if (y.z < 0.f) y.z *= a;
        if (y.w < 0.f) y.w *= a;
    }
    *(float4*)&Y[i4] = y;
}

extern "C" void kernel_launch(void* const* d_in, const int* in_sizes, int n_in,
                              void* d_out, int out_size, void* d_ws, size_t ws_size,
                              hipStream_t stream) {
    const float* x = (const float*)d_in[0];
    const int* ei = (const int*)d_in[1];
    const float* w0a = (const float*)d_in[2];
    const float* b0a = (const float*)d_in[3];
    const float* w0b = (const float*)d_in[4];
    const float* b0b = (const float*)d_in[5];
    const float* w1a = (const float*)d_in[6];
    const float* b1a = (const float*)d_in[7];
    const float* w1b = (const float*)d_in[8];
    const float* b1b = (const float*)d_in[9];
    const float* bng = (const float*)d_in[10];
    const float* bnb = (const float*)d_in[11];
    const float* pw  = (const float*)d_in[12];
    const float* pb  = (const float*)d_in[13];
    const float* pbng = (const float*)d_in[14];
    const float* pbnb = (const float*)d_in[15];
    const float* pa = (const float*)d_in[16];

    float* outZ = (float*)d_out;                    // (NN,128) f32 — z
    float* outP = outZ + (size_t)NN * HD;           // (NN,128) f32 — p (also z1 scratch)

    float* ws = (float*)d_ws;
    float* bufH = ws;                               // (NN,128) f32 — aggregate
    float* st = bufH + (size_t)NN * HD;             // 1024 floats of stats
    int* deg = (int*)(st + 1024);                   // NN
    int* rowptr = deg + NN;                         // NN+1 (+pad)
    int* cur = rowptr + NN + 64;                    // NN
    int* esrc = cur + NN;                           // NE
    int* bsum = esrc + NE;                          // 256
    int* bbase = bsum + 256;                        // 256
    __bf16* wth = (__bf16*)(bbase + 256);           // 5*128*128 bf16 hi (packed)
    __bf16* wtl = wth + 5 * HD * HD;                // 5*128*128 bf16 lo (packed)

    const int* srcv = ei;
    const int* dstv = ei + NE;

    const int EB = NE / 256;                        // 3125 edge blocks
    const int NB = NB_SCAN;                         // 196 node blocks
    const int ELV = (NN * HD) / (256 * 4);          // 6250 float4 elementwise blocks
    const int GB = (NN + 63) / 64;                  // 782 GEMM blocks
    const int AB = NN / 8;                          // 6250 agg blocks

    // ---- W pre-split/pack + CSR build + stat zeroing ----
    k_wprep<<<dim3(HD, 5), HD, 0, stream>>>(w0a, w0b, w1a, w1b, pw, wth, wtl);
    k_zero_f<<<4, 256, 0, stream>>>(st, 1024);
    k_zero_i<<<NB, 256, 0, stream>>>(deg, NN);
    k_hist<<<EB, 256, 0, stream>>>(dstv, deg);
    k_blocksum<<<NB, 256, 0, stream>>>(deg, bsum);
    k_scanpart<<<1, 256, 0, stream>>>(bsum, bbase);
    k_scanfin<<<NB, 256, 0, stream>>>(deg, bbase, rowptr, cur);
    k_fill<<<EB, 256, 0, stream>>>(srcv, dstv, cur, esrc);

    // ---- GIN layer 0: z1 = relu(MLP0(x + agg(x))) ----
    k_agg<<<AB, 256, 0, stream>>>(x, rowptr, esrc, bufH);
    k_mlp<0><<<GB, 256, 0, stream>>>(bufH, wth + 0 * HD * HD, wtl + 0 * HD * HD, b0a,
                                     wth + 1 * HD * HD, wtl + 1 * HD * HD, b0b,
                                     outP, nullptr, nullptr);

    // ---- GIN layer 1: z2 = relu(MLP1(z1 + agg(z1))), fused z-stats ----
    k_agg<<<AB, 256, 0, stream>>>(outP, rowptr, esrc, bufH);
    k_mlp<1><<<GB, 256, 0, stream>>>(bufH, wth + 2 * HD * HD, wtl + 2 * HD * HD, b1a,
                                     wth + 3 * HD * HD, wtl + 3 * HD * HD, b1b,
                                     outZ, st + 0, st + 128);

    // ---- encoder BatchNorm -> z output (in place) ----
    k_bnfin<<<1, 128, 0, stream>>>(st + 0, st + 128, bng, bnb, st + 256, st + 384);
    k_bnapply<0><<<ELV, 256, 0, stream>>>(outZ, st + 256, st + 384, outZ, pa);

    // ---- projection head: linear (fused p-stats) -> BN -> PReLU ----
    k_proj<<<GB, 256, 0, stream>>>(outZ, wth + 4 * HD * HD, wtl + 4 * HD * HD, pb,
                                   outP, st + 512, st + 640);
    k_bnfin<<<1, 128, 0, stream>>>(st + 512, st + 640, pbng, pbnb, st + 768, st + 896);
    k_bnapply<1><<<ELV, 256, 0, stream>>>(outP, st + 768, st + 896, outP, pa);
}

// Round 11
// 445.070 us; speedup vs baseline: 1.2412x; 1.0619x over previous
//
#include <hip/hip_runtime.h>
#include <hip/hip_bf16.h>

#define NN 50000
#define NE 800000
#define HD 128
#define BN_EPS 1e-5f
#define NB_SCAN 196  // ceil(NN/256)
#define MSTR 132     // padded LDS stride (floats)

typedef __attribute__((ext_vector_type(8))) __bf16 bf16x8;
typedef __attribute__((ext_vector_type(4))) float floatx4;

// ---------------- zero helpers ----------------
__global__ void k_zero_f(float* __restrict__ p, int n) {
    const int i = blockIdx.x * 256 + threadIdx.x;
    if (i < n) p[i] = 0.f;
}
__global__ void k_zero_i(int* __restrict__ p, int n) {
    const int i = blockIdx.x * 256 + threadIdx.x;
    if (i < n) p[i] = 0;
}

// ---------------- W prep: split bf16 hi/lo, packed in wave-load order ----------------
// offset(m, n, k) = m*HD*HD + ((ct*4 + ks)*64 + lane)*8 + j
__global__ void k_wprep(const float* __restrict__ W0, const float* __restrict__ W1,
                        const float* __restrict__ W2, const float* __restrict__ W3,
                        const float* __restrict__ W4,
                        __bf16* __restrict__ Bh, __bf16* __restrict__ Bl) {
    const int n = blockIdx.x, m = blockIdx.y, k = threadIdx.x;
    const float* W = (m == 0) ? W0 : (m == 1) ? W1 : (m == 2) ? W2 : (m == 3) ? W3 : W4;
    const float w = W[k * HD + n];
    const __bf16 h = (__bf16)w;
    const int ct = n >> 4, lm = n & 15;
    const int ks = k >> 5, lq = (k & 31) >> 3, j = k & 7;
    const int lane = lq * 16 + lm;
    const size_t o = (size_t)m * HD * HD + (size_t)(((ct * 4 + ks) * 64) + lane) * 8 + j;
    Bh[o] = h;
    Bl[o] = (__bf16)(w - (float)h);
}

// ---------------- CSR build ----------------
__global__ void k_hist(const int* __restrict__ dst, int* __restrict__ deg) {
    const int e = blockIdx.x * 256 + threadIdx.x;
    atomicAdd(&deg[dst[e]], 1);
}

__global__ __launch_bounds__(256) void k_blocksum(const int* __restrict__ deg,
                                                  int* __restrict__ bsum) {
    __shared__ int sh[256];
    const int t = threadIdx.x;
    const int i = blockIdx.x * 256 + t;
    sh[t] = (i < NN) ? deg[i] : 0;
    __syncthreads();
#pragma unroll
    for (int s = 128; s > 0; s >>= 1) {
        if (t < s) sh[t] += sh[t + s];
        __syncthreads();
    }
    if (t == 0) bsum[blockIdx.x] = sh[0];
}

__global__ __launch_bounds__(256) void k_scanpart(const int* __restrict__ bsum,
                                                  int* __restrict__ bbase) {
    __shared__ int sh[256];
    const int t = threadIdx.x;
    const int v = (t < NB_SCAN) ? bsum[t] : 0;
    sh[t] = v;
    __syncthreads();
#pragma unroll
    for (int s = 1; s < 256; s <<= 1) {
        int add = (t >= s) ? sh[t - s] : 0;
        __syncthreads();
        sh[t] += add;
        __syncthreads();
    }
    if (t < NB_SCAN) bbase[t] = sh[t] - v;  // exclusive
}

__global__ __launch_bounds__(256) void k_scanfin(const int* __restrict__ deg,
                                                 const int* __restrict__ bbase,
                                                 int* __restrict__ rowptr,
                                                 int* __restrict__ cur) {
    __shared__ int sh[256];
    const int t = threadIdx.x;
    const int i = blockIdx.x * 256 + t;
    const int v = (i < NN) ? deg[i] : 0;
    sh[t] = v;
    __syncthreads();
#pragma unroll
    for (int s = 1; s < 256; s <<= 1) {
        int add = (t >= s) ? sh[t - s] : 0;
        __syncthreads();
        sh[t] += add;
        __syncthreads();
    }
    const int incl = sh[t] + bbase[blockIdx.x];
    if (i < NN) {
        const int excl = incl - v;
        rowptr[i] = excl;
        cur[i] = excl;
        if (i == NN - 1) rowptr[NN] = incl;
    }
}

__global__ void k_fill(const int* __restrict__ src, const int* __restrict__ dst,
                       int* __restrict__ cur, int* __restrict__ esrc) {
    const int e = blockIdx.x * 256 + threadIdx.x;
    const int p = atomicAdd(&cur[dst[e]], 1);
    esrc[p] = src[e];
}

// ---------------- gather-aggregate: H[i] = Z[i] + sum_{j->i} Z[j] ----------------
__global__ __launch_bounds__(256) void k_agg(const float* __restrict__ Z,
                                             const int* __restrict__ rowptr,
                                             const int* __restrict__ esrc,
                                             float* __restrict__ H) {
    const int g = threadIdx.x >> 5;
    const int lc = threadIdx.x & 31;
    const int node = blockIdx.x * 8 + g;
    const int c4 = lc * 4;
    const int start = rowptr[node], end = rowptr[node + 1];
    float4 acc = *(const float4*)&Z[(size_t)node * HD + c4];
    int k = start;
    for (; k + 4 <= end; k += 4) {
        const int s0 = esrc[k], s1 = esrc[k + 1], s2 = esrc[k + 2], s3 = esrc[k + 3];
        const float4 v0 = *(const float4*)&Z[(size_t)s0 * HD + c4];
        const float4 v1 = *(const float4*)&Z[(size_t)s1 * HD + c4];
        const float4 v2 = *(const float4*)&Z[(size_t)s2 * HD + c4];
        const float4 v3 = *(const float4*)&Z[(size_t)s3 * HD + c4];
        acc.x += v0.x + v1.x + v2.x + v3.x;
        acc.y += v0.y + v1.y + v2.y + v3.y;
        acc.z += v0.z + v1.z + v2.z + v3.z;
        acc.w += v0.w + v1.w + v2.w + v3.w;
    }
    for (; k < end; ++k) {
        const int s = esrc[k];
        const float4 v = *(const float4*)&Z[(size_t)s * HD + c4];
        acc.x += v.x; acc.y += v.y; acc.z += v.z; acc.w += v.w;
    }
    *(float4*)&H[(size_t)node * HD + c4] = acc;
}

// ---------------- helper: split float8 into bf16 hi/lo fragments ----------------
__device__ __forceinline__ void split8(const float4 a, const float4 b,
                                       bf16x8& hi, bf16x8& lo) {
    hi[0] = (__bf16)a.x; lo[0] = (__bf16)(a.x - (float)hi[0]);
    hi[1] = (__bf16)a.y; lo[1] = (__bf16)(a.y - (float)hi[1]);
    hi[2] = (__bf16)a.z; lo[2] = (__bf16)(a.z - (float)hi[2]);
    hi[3] = (__bf16)a.w; lo[3] = (__bf16)(a.w - (float)hi[3]);
    hi[4] = (__bf16)b.x; lo[4] = (__bf16)(b.x - (float)hi[4]);
    hi[5] = (__bf16)b.y; lo[5] = (__bf16)(b.y - (float)hi[5]);
    hi[6] = (__bf16)b.z; lo[6] = (__bf16)(b.z - (float)hi[6]);
    hi[7] = (__bf16)b.w; lo[7] = (__bf16)(b.w - (float)hi[7]);
}

// ---------------- helper: one bf16x3 GEMM K-pass over a 16-row wave tile ----------------
__device__ __forceinline__ void mfma_pass(floatx4 (&acc)[8], const bf16x8 ah,
                                          const bf16x8 al, const __bf16* Bh,
                                          const __bf16* Bl, int ks, int lane) {
#pragma unroll
    for (int ct = 0; ct < 8; ++ct) {
        const size_t bo = (size_t)(((ct * 4 + ks) * 64) + lane) * 8;
        const bf16x8 bh = *(const bf16x8*)&Bh[bo];
        const bf16x8 bl = *(const bf16x8*)&Bl[bo];
        acc[ct] = __builtin_amdgcn_mfma_f32_16x16x32_bf16(al, bh, acc[ct], 0, 0, 0);
        acc[ct] = __builtin_amdgcn_mfma_f32_16x16x32_bf16(ah, bl, acc[ct], 0, 0, 0);
        acc[ct] = __builtin_amdgcn_mfma_f32_16x16x32_bf16(ah, bh, acc[ct], 0, 0, 0);
    }
}

// ---------------- fused GIN MLP: C = relu(relu(A@W1+b1)@W2+b2), optional col stats ----------------
// 4 waves x 16 rows; mid in per-wave LDS; C-write via LDS transpose -> coalesced float4 stores.
template <int STATS>
__global__ __launch_bounds__(256) void k_mlp(const float* __restrict__ A,
                                             const __bf16* __restrict__ Bh1,
                                             const __bf16* __restrict__ Bl1,
                                             const float* __restrict__ b1,
                                             const __bf16* __restrict__ Bh2,
                                             const __bf16* __restrict__ Bl2,
                                             const float* __restrict__ b2,
                                             float* __restrict__ C,
                                             float* __restrict__ gsum,
                                             float* __restrict__ gsq) {
    __shared__ float mid[4][16 * MSTR];   // 33792 B, per-wave scratch
    __shared__ float ssum[128], ssq[128];
    const int tid = threadIdx.x;
    const int wid = tid >> 6, lane = tid & 63;
    const int lq = lane >> 4, lm = lane & 15;
    if (STATS) {
        if (tid < 128) { ssum[tid] = 0.f; ssq[tid] = 0.f; }
        __syncthreads();
    }
    const int rowbase = blockIdx.x * 64 + wid * 16;
    const int r0 = min(rowbase + lm, NN - 1);
    float* m = &mid[wid][0];

    // ---- GEMM1: mid = relu(A@W1 + b1) ----
    floatx4 acc[8];
#pragma unroll
    for (int j = 0; j < 8; ++j) acc[j] = (floatx4){0.f, 0.f, 0.f, 0.f};
#pragma unroll
    for (int ks = 0; ks < 4; ++ks) {
        const int kk = ks * 32 + lq * 8;
        const float4 aa = *(const float4*)&A[(size_t)r0 * HD + kk];
        const float4 ab = *(const float4*)&A[(size_t)r0 * HD + kk + 4];
        bf16x8 ah, al;
        split8(aa, ab, ah, al);
        mfma_pass(acc, ah, al, Bh1, Bl1, ks, lane);
    }
#pragma unroll
    for (int ct = 0; ct < 8; ++ct) {
        const int col = ct * 16 + lm;
        const float bcol = b1[col];
#pragma unroll
        for (int r = 0; r < 4; ++r)
            m[(lq * 4 + r) * MSTR + col] = fmaxf(acc[ct][r] + bcol, 0.f);
    }
    // ---- GEMM2: C = relu(mid@W2 + b2) ----
#pragma unroll
    for (int j = 0; j < 8; ++j) acc[j] = (floatx4){0.f, 0.f, 0.f, 0.f};
#pragma unroll
    for (int ks = 0; ks < 4; ++ks) {
        const int kk = ks * 32 + lq * 8;
        const float4 aa = *(const float4*)&m[lm * MSTR + kk];
        const float4 ab = *(const float4*)&m[lm * MSTR + kk + 4];
        bf16x8 ah, al;
        split8(aa, ab, ah, al);
        mfma_pass(acc, ah, al, Bh2, Bl2, ks, lane);
    }
    // ---- epilogue: transpose via LDS -> coalesced float4 stores (+stats) ----
#pragma unroll
    for (int ct = 0; ct < 8; ++ct) {
        const int col = ct * 16 + lm;
        const float bcol = b2[col];
#pragma unroll
        for (int r = 0; r < 4; ++r)
            m[(lq * 4 + r) * MSTR + col] = fmaxf(acc[ct][r] + bcol, 0.f);
    }
    float s0 = 0.f, s1 = 0.f, s2 = 0.f, s3 = 0.f;
    float q0 = 0.f, q1 = 0.f, q2 = 0.f, q3 = 0.f;
    const int c0 = (lane * 4) & 127;
#pragma unroll
    for (int p = 0; p < 8; ++p) {
        const int idx = p * 256 + lane * 4;
        const int r = idx >> 7;
        const float4 v = *(const float4*)&m[r * MSTR + c0];
        const int row = rowbase + r;
        if (row < NN) {
            *(float4*)&C[(size_t)row * HD + c0] = v;
            if (STATS) {
                s0 += v.x; q0 = fmaf(v.x, v.x, q0);
                s1 += v.y; q1 = fmaf(v.y, v.y, q1);
                s2 += v.z; q2 = fmaf(v.z, v.z, q2);
                s3 += v.w; q3 = fmaf(v.w, v.w, q3);
            }
        }
    }
    if (STATS) {
        s0 += __shfl_xor(s0, 32); q0 += __shfl_xor(q0, 32);
        s1 += __shfl_xor(s1, 32); q1 += __shfl_xor(q1, 32);
        s2 += __shfl_xor(s2, 32); q2 += __shfl_xor(q2, 32);
        s3 += __shfl_xor(s3, 32); q3 += __shfl_xor(q3, 32);
        if (lane < 32) {
            atomicAdd(&ssum[c0 + 0], s0); atomicAdd(&ssq[c0 + 0], q0);
            atomicAdd(&ssum[c0 + 1], s1); atomicAdd(&ssq[c0 + 1], q1);
            atomicAdd(&ssum[c0 + 2], s2); atomicAdd(&ssq[c0 + 2], q2);
            atomicAdd(&ssum[c0 + 3], s3); atomicAdd(&ssq[c0 + 3], q3);
        }
        __syncthreads();
        if (tid < 128) {
            atomicAdd(&gsum[tid], ssum[tid]);
            atomicAdd(&gsq[tid], ssq[tid]);
        }
    }
}

// ---------------- projection GEMM with fused BN-on-A + z-write + p stats ----------------
// A' = scale[k]*z2 + shift[k] (= z, written to Zout); P = A'@W + b; col stats on P.
__global__ __launch_bounds__(256) void k_proj(const float* __restrict__ Z2,
                                              const float* __restrict__ bnsc,
                                              const float* __restrict__ bnsh,
                                              float* __restrict__ Zout,
                                              const __bf16* __restrict__ Bh,
                                              const __bf16* __restrict__ Bl,
                                              const float* __restrict__ bias,
                                              float* __restrict__ C,
                                              float* __restrict__ gsum,
                                              float* __restrict__ gsq) {
    __shared__ float tb[4][16 * MSTR];
    __shared__ float ssum[128], ssq[128];
    const int tid = threadIdx.x;
    const int wid = tid >> 6, lane = tid & 63;
    const int lq = lane >> 4, lm = lane & 15;
    if (tid < 128) { ssum[tid] = 0.f; ssq[tid] = 0.f; }
    __syncthreads();
    const int rowbase = blockIdx.x * 64 + wid * 16;
    const int r0 = min(rowbase + lm, NN - 1);
    const bool rowok = (rowbase + lm) < NN;
    float* m = &tb[wid][0];

    floatx4 acc[8];
#pragma unroll
    for (int j = 0; j < 8; ++j) acc[j] = (floatx4){0.f, 0.f, 0.f, 0.f};
#pragma unroll
    for (int ks = 0; ks < 4; ++ks) {
        const int kk = ks * 32 + lq * 8;
        const float4 za = *(const float4*)&Z2[(size_t)r0 * HD + kk];
        const float4 zb = *(const float4*)&Z2[(size_t)r0 * HD + kk + 4];
        const float4 sca = *(const float4*)&bnsc[kk];
        const float4 scb = *(const float4*)&bnsc[kk + 4];
        const float4 sha = *(const float4*)&bnsh[kk];
        const float4 shb = *(const float4*)&bnsh[kk + 4];
        float4 aa, ab;
        aa.x = fmaf(za.x, sca.x, sha.x); aa.y = fmaf(za.y, sca.y, sha.y);
        aa.z = fmaf(za.z, sca.z, sha.z); aa.w = fmaf(za.w, sca.w, sha.w);
        ab.x = fmaf(zb.x, scb.x, shb.x); ab.y = fmaf(zb.y, scb.y, shb.y);
        ab.z = fmaf(zb.z, scb.z, shb.z); ab.w = fmaf(zb.w, scb.w, shb.w);
        if (rowok) {
            *(float4*)&Zout[(size_t)r0 * HD + kk] = aa;
            *(float4*)&Zout[(size_t)r0 * HD + kk + 4] = ab;
        }
        bf16x8 ah, al;
        split8(aa, ab, ah, al);
        mfma_pass(acc, ah, al, Bh, Bl, ks, lane);
    }
    // ---- epilogue: transpose -> coalesced stores + stats ----
#pragma unroll
    for (int ct = 0; ct < 8; ++ct) {
        const int col = ct * 16 + lm;
        const float bcol = bias[col];
#pragma unroll
        for (int r = 0; r < 4; ++r)
            m[(lq * 4 + r) * MSTR + col] = acc[ct][r] + bcol;
    }
    float s0 = 0.f, s1 = 0.f, s2 = 0.f, s3 = 0.f;
    float q0 = 0.f, q1 = 0.f, q2 = 0.f, q3 = 0.f;
    const int c0 = (lane * 4) & 127;
#pragma unroll
    for (int p = 0; p < 8; ++p) {
        const int idx = p * 256 + lane * 4;
        const int r = idx >> 7;
        const float4 v = *(const float4*)&m[r * MSTR + c0];
        const int row = rowbase + r;
        if (row < NN) {
            *(float4*)&C[(size_t)row * HD + c0] = v;
            s0 += v.x; q0 = fmaf(v.x, v.x, q0);
            s1 += v.y; q1 = fmaf(v.y, v.y, q1);
            s2 += v.z; q2 = fmaf(v.z, v.z, q2);
            s3 += v.w; q3 = fmaf(v.w, v.w, q3);
        }
    }
    s0 += __shfl_xor(s0, 32); q0 += __shfl_xor(q0, 32);
    s1 += __shfl_xor(s1, 32); q1 += __shfl_xor(q1, 32);
    s2 += __shfl_xor(s2, 32); q2 += __shfl_xor(q2, 32);
    s3 += __shfl_xor(s3, 32); q3 += __shfl_xor(q3, 32);
    if (lane < 32) {
        atomicAdd(&ssum[c0 + 0], s0); atomicAdd(&ssq[c0 + 0], q0);
        atomicAdd(&ssum[c0 + 1], s1); atomicAdd(&ssq[c0 + 1], q1);
        atomicAdd(&ssum[c0 + 2], s2); atomicAdd(&ssq[c0 + 2], q2);
        atomicAdd(&ssum[c0 + 3], s3); atomicAdd(&ssq[c0 + 3], q3);
    }
    __syncthreads();
    if (tid < 128) {
        atomicAdd(&gsum[tid], ssum[tid]);
        atomicAdd(&gsq[tid], ssq[tid]);
    }
}

// ---------------- BN finalize ----------------
__global__ void k_bnfin(const float* __restrict__ sum, const float* __restrict__ sumsq,
                        const float* __restrict__ gamma, const float* __restrict__ beta,
                        float* __restrict__ scale, float* __restrict__ shift) {
    const int c = threadIdx.x;
    const float mean = sum[c] * (1.f / NN);
    const float var = sumsq[c] * (1.f / NN) - mean * mean;
    const float sc = gamma[c] * rsqrtf(var + BN_EPS);
    scale[c] = sc;
    shift[c] = beta[c] - mean * sc;
}

// ---------------- BN apply + PReLU, float4, in-place ----------------
__global__ void k_bnapply(const float* __restrict__ X, const float* __restrict__ scale,
                          const float* __restrict__ shift, float* __restrict__ Y,
                          const float* __restrict__ pa) {
    const int i4 = (blockIdx.x * 256 + threadIdx.x) * 4;
    const int c = i4 & 127;
    const float4 sc = *(const float4*)&scale[c];
    const float4 sh = *(const float4*)&shift[c];
    const float4 v = *(const float4*)&X[i4];
    float4 y;
    y.x = fmaf(v.x, sc.x, sh.x);
    y.y = fmaf(v.y, sc.y, sh.y);
    y.z = fmaf(v.z, sc.z, sh.z);
    y.w = fmaf(v.w, sc.w, sh.w);
    const float a = pa[0];
    if (y.x < 0.f) y.x *= a;
    if (y.y < 0.f) y.y *= a;
    if (y.z < 0.f) y.z *= a;
    if (y.w < 0.f) y.w *= a;
    *(float4*)&Y[i4] = y;
}

extern "C" void kernel_launch(void* const* d_in, const int* in_sizes, int n_in,
                              void* d_out, int out_size, void* d_ws, size_t ws_size,
                              hipStream_t stream) {
    const float* x = (const float*)d_in[0];
    const int* ei = (const int*)d_in[1];
    const float* w0a = (const float*)d_in[2];
    const float* b0a = (const float*)d_in[3];
    const float* w0b = (const float*)d_in[4];
    const float* b0b = (const float*)d_in[5];
    const float* w1a = (const float*)d_in[6];
    const float* b1a = (const float*)d_in[7];
    const float* w1b = (const float*)d_in[8];
    const float* b1b = (const float*)d_in[9];
    const float* bng = (const float*)d_in[10];
    const float* bnb = (const float*)d_in[11];
    const float* pw  = (const float*)d_in[12];
    const float* pb  = (const float*)d_in[13];
    const float* pbng = (const float*)d_in[14];
    const float* pbnb = (const float*)d_in[15];
    const float* pa = (const float*)d_in[16];

    float* outZ = (float*)d_out;                    // (NN,128) f32 — z
    float* outP = outZ + (size_t)NN * HD;           // (NN,128) f32 — z1 / z2 / p

    float* ws = (float*)d_ws;
    float* bufH = ws;                               // (NN,128) f32 — aggregate
    float* st = bufH + (size_t)NN * HD;             // 1024 floats of stats
    int* deg = (int*)(st + 1024);                   // NN
    int* rowptr = deg + NN;                         // NN+1 (+pad)
    int* cur = rowptr + NN + 64;                    // NN
    int* esrc = cur + NN;                           // NE
    int* bsum = esrc + NE;                          // 256
    int* bbase = bsum + 256;                        // 256
    __bf16* wth = (__bf16*)(bbase + 256);           // 5*128*128 bf16 hi (packed)
    __bf16* wtl = wth + 5 * HD * HD;                // 5*128*128 bf16 lo (packed)

    const int* srcv = ei;
    const int* dstv = ei + NE;

    const int EB = NE / 256;
    const int NB = NB_SCAN;
    const int ELV = (NN * HD) / (256 * 4);
    const int GB = (NN + 63) / 64;                  // 782
    const int AB = NN / 8;                          // 6250

    // ---- W pre-split/pack + CSR build + stat zeroing ----
    k_wprep<<<dim3(HD, 5), HD, 0, stream>>>(w0a, w0b, w1a, w1b, pw, wth, wtl);
    k_zero_f<<<4, 256, 0, stream>>>(st, 1024);
    k_zero_i<<<NB, 256, 0, stream>>>(deg, NN);
    k_hist<<<EB, 256, 0, stream>>>(dstv, deg);
    k_blocksum<<<NB, 256, 0, stream>>>(deg, bsum);
    k_scanpart<<<1, 256, 0, stream>>>(bsum, bbase);
    k_scanfin<<<NB, 256, 0, stream>>>(deg, bbase, rowptr, cur);
    k_fill<<<EB, 256, 0, stream>>>(srcv, dstv, cur, esrc);

    // ---- GIN layer 0: z1 = relu(MLP0(x + agg(x))) -> outP ----
    k_agg<<<AB, 256, 0, stream>>>(x, rowptr, esrc, bufH);
    k_mlp<0><<<GB, 256, 0, stream>>>(bufH, wth + 0 * HD * HD, wtl + 0 * HD * HD, b0a,
                                     wth + 1 * HD * HD, wtl + 1 * HD * HD, b0b,
                                     outP, nullptr, nullptr);

    // ---- GIN layer 1: z2 = relu(MLP1(z1 + agg(z1))) -> outP, fused z-stats ----
    k_agg<<<AB, 256, 0, stream>>>(outP, rowptr, esrc, bufH);
    k_mlp<1><<<GB, 256, 0, stream>>>(bufH, wth + 2 * HD * HD, wtl + 2 * HD * HD, b1a,
                                     wth + 3 * HD * HD, wtl + 3 * HD * HD, b1b,
                                     outP, st + 0, st + 128);

    // ---- z BN finalize; proj fuses BN-apply + z-write + p-stats (in-place on outP) ----
    k_bnfin<<<1, 128, 0, stream>>>(st + 0, st + 128, bng, bnb, st + 256, st + 384);
    k_proj<<<GB, 256, 0, stream>>>(outP, st + 256, st + 384, outZ,
                                   wth + 4 * HD * HD, wtl + 4 * HD * HD, pb,
                                   outP, st + 512, st + 640);

    // ---- p BN -> PReLU (in place) ----
    k_bnfin<<<1, 128, 0, stream>>>(st + 512, st + 640, pbng, pbnb, st + 768, st + 896);
    k_bnapply<<<ELV, 256, 0, stream>>>(outP, st + 768, st + 896, outP, pa);
}